// Round 5
// baseline (1116.315 us; speedup 1.0000x reference)
//
#include <hip/hip_runtime.h>

#define NN 20000
#define NE 320000
#define HD 128

typedef short     s16x8 __attribute__((ext_vector_type(8)));
typedef unsigned short u16x8 __attribute__((ext_vector_type(8)));
typedef unsigned short u16x4 __attribute__((ext_vector_type(4)));
typedef float     f32x4 __attribute__((ext_vector_type(4)));

__device__ __forceinline__ float b2f(unsigned short u) {
    union { unsigned int i; float f; } c; c.i = ((unsigned int)u) << 16; return c.f;
}
__device__ __forceinline__ unsigned short f2b(float f) {
    union { float f; unsigned int i; } c; c.f = f;
    unsigned int x = c.i + 0x7FFFu + ((c.i >> 16) & 1u);
    return (unsigned short)(x >> 16);
}

__global__ void cvt_bf16(const float* __restrict__ in, unsigned short* __restrict__ out, int n) {
    int i = blockIdx.x * 256 + threadIdx.x;
    if (i < n) out[i] = f2b(in[i]);
}

// WT[n*K + k] = bf16(W[k*128 + n])
__global__ void cvt_transpose(const float* __restrict__ W, unsigned short* __restrict__ WT, int K) {
    int tid = blockIdx.x * 256 + threadIdx.x;
    if (tid >= K * HD) return;
    int n = tid & (HD - 1), k = tid >> 7;
    WT[(size_t)n * K + k] = f2b(W[(size_t)k * HD + n]);
}

// ---------------- CSR build (sort edges by dst) ----------------
__global__ void hist_kernel(const int* __restrict__ ei, int* __restrict__ cnt) {
    int e = blockIdx.x * 256 + threadIdx.x;
    if (e < NE) atomicAdd(&cnt[ei[NE + e]], 1);
}

__global__ void scan_kernel(const int* __restrict__ cnt, int* __restrict__ rowptr) {
    __shared__ int s[256];
    __shared__ int carry;
    int t = threadIdx.x;
    if (t == 0) carry = 0;
    __syncthreads();
    for (int base = 0; base < NN; base += 256) {
        int v = (base + t < NN) ? cnt[base + t] : 0;
        s[t] = v; __syncthreads();
        #pragma unroll
        for (int off = 1; off < 256; off <<= 1) {
            int add = (t >= off) ? s[t - off] : 0;
            __syncthreads();
            s[t] += add;
            __syncthreads();
        }
        int incl = s[t];
        if (base + t < NN) rowptr[base + t] = carry + incl - v;
        __syncthreads();
        if (t == 255) carry += incl;
        __syncthreads();
    }
    if (t == 0) rowptr[NN] = NE;
}

// pos assignment + pre-gather of src, dst, edge attrs into sorted order
__global__ void scatter_kernel(const int* __restrict__ ei, const float* __restrict__ ea,
                               const int* __restrict__ rowptr, int* __restrict__ cursor,
                               int* __restrict__ srcS, int* __restrict__ dstS,
                               float* __restrict__ eaS, unsigned short* __restrict__ eaSB) {
    int e = blockIdx.x * 256 + threadIdx.x;
    if (e >= NE) return;
    int d = ei[NE + e];
    int pos = rowptr[d] + atomicAdd(&cursor[d], 1);
    srcS[pos] = ei[e];
    dstS[pos] = d;
    float4 v = *(const float4*)(ea + (long long)e * 4);
    *(float4*)(eaS + (long long)pos * 4) = v;
    u16x4 b; b[0] = f2b(v.x); b[1] = f2b(v.y); b[2] = f2b(v.z); b[3] = f2b(v.w);
    *(u16x4*)(eaSB + (long long)pos * 4) = b;
}

// segment-sum for layer 1 (bf16 msg -> bf16 Agg)
__global__ void agg_kernel(const unsigned short* __restrict__ msg,
                           const int* __restrict__ rowptr,
                           unsigned short* __restrict__ AggB) {
    int t = threadIdx.x;
    int n = blockIdx.x * 16 + (t >> 4);
    int cg = t & 15;
    if (n >= NN) return;
    int s = rowptr[n], e = rowptr[n + 1];
    float a[8];
    #pragma unroll
    for (int j = 0; j < 8; ++j) a[j] = 0.f;
    for (int p = s; p < e; ++p) {
        u16x8 v = *(const u16x8*)(msg + (long long)p * HD + cg * 8);
        #pragma unroll
        for (int j = 0; j < 8; ++j) a[j] += b2f(v[j]);
    }
    u16x8 o;
    #pragma unroll
    for (int j = 0; j < 8; ++j) o[j] = f2b(a[j]);
    *(u16x8*)(AggB + (long long)n * HD + cg * 8) = o;
}

// ---------------- fused edge MFMA + segment aggregation ----------------
// rows = sorted edge positions; A row = seg1[srcS[pos]] slice (K bf16).
// msg = relu(A@W + bias + ea@Wea) computed in-tile; segment-summed by dstS runs.
// Interior nodes: plain fp32 store to Agg. Boundary nodes: fp32 atomicAdd.
#define TSTR 132
__global__ __launch_bounds__(256)
void mfma_edge_agg(const unsigned short* __restrict__ seg1, long long s1, int xoff, int K,
                   const int* __restrict__ srcS, const int* __restrict__ dstS,
                   const int* __restrict__ rowptr,
                   const unsigned short* __restrict__ WT,   // [128][K] bf16
                   const float* __restrict__ bias,
                   const float* __restrict__ Wea,           // [4][128] fp32
                   const float* __restrict__ eaS,           // [E][4] fp32 sorted
                   float* __restrict__ Agg)                 // [NN][128] fp32, pre-zeroed
{
    __shared__ unsigned short As[4 * 128 * 8];
    __shared__ unsigned short Bs[4 * 128 * 8];
    __shared__ float eas[128 * 4];
    __shared__ unsigned short Ts[128 * TSTR];   // [col][row] bf16 tile
    __shared__ int dstL[128];

    const int t    = threadIdx.x;
    const int lane = t & 63;
    const int wid  = t >> 6;
    const int wm   = wid >> 1, wn = wid & 1;
    const int ln   = lane & 15, kb = lane >> 4;
    const int bRow = blockIdx.x * 128;

    const int srow = t >> 1, half = t & 1;
    long long r1 = srcS[bRow + srow];
    const unsigned short* p1 = seg1 + r1 * s1 + xoff;
    const unsigned short* pb = WT + (long long)srow * K;
    const int c0 = half * 2, c1 = half * 2 + 1;

    if (t < 128) {
        *(float4*)&eas[t * 4] = *(const float4*)(eaS + (long long)(bRow + t) * 4);
        dstL[t] = dstS[bRow + t];
    }

    f32x4 acc[4][4];
    #pragma unroll
    for (int m = 0; m < 4; ++m)
        #pragma unroll
        for (int n = 0; n < 4; ++n) acc[m][n] = f32x4{0.f, 0.f, 0.f, 0.f};

    const int nkt = K >> 5;
    for (int kt = 0; kt < nkt; ++kt) {
        int k0 = (kt << 5) + half * 16;
        const u16x8* sp = (const u16x8*)(p1 + k0);
        u16x8 a0 = sp[0], a1 = sp[1];
        *(u16x8*)&As[(c0 * 128 + srow) * 8] = a0;
        *(u16x8*)&As[(c1 * 128 + srow) * 8] = a1;
        const u16x8* bp = (const u16x8*)(pb + (kt << 5) + half * 16);
        u16x8 b0 = bp[0], b1 = bp[1];
        *(u16x8*)&Bs[(c0 * 128 + srow) * 8] = b0;
        *(u16x8*)&Bs[(c1 * 128 + srow) * 8] = b1;
        __syncthreads();

        s16x8 af[4], bfr[4];
        #pragma unroll
        for (int m = 0; m < 4; ++m)
            af[m] = *(const s16x8*)&As[(kb * 128 + wm * 64 + m * 16 + ln) * 8];
        #pragma unroll
        for (int n = 0; n < 4; ++n)
            bfr[n] = *(const s16x8*)&Bs[(kb * 128 + wn * 64 + n * 16 + ln) * 8];
        #pragma unroll
        for (int m = 0; m < 4; ++m)
            #pragma unroll
            for (int n = 0; n < 4; ++n)
                acc[m][n] = __builtin_amdgcn_mfma_f32_16x16x32_bf16(af[m], bfr[n], acc[m][n], 0, 0, 0);
        __syncthreads();
    }

    float bv[4], we[4][4];
    #pragma unroll
    for (int n = 0; n < 4; ++n) bv[n] = bias[wn * 64 + n * 16 + ln];
    #pragma unroll
    for (int c = 0; c < 4; ++c)
        #pragma unroll
        for (int n = 0; n < 4; ++n) we[c][n] = Wea[c * HD + wn * 64 + n * 16 + ln];

    #pragma unroll
    for (int m = 0; m < 4; ++m) {
        int row0 = wm * 64 + m * 16 + kb * 4;
        float4 e4[4];
        #pragma unroll
        for (int r = 0; r < 4; ++r) e4[r] = *(const float4*)&eas[(row0 + r) * 4];
        #pragma unroll
        for (int n = 0; n < 4; ++n) {
            int col = wn * 64 + n * 16 + ln;
            u16x4 wv;
            #pragma unroll
            for (int r = 0; r < 4; ++r) {
                float v = acc[m][n][r] + bv[n]
                        + e4[r].x * we[0][n] + e4[r].y * we[1][n]
                        + e4[r].z * we[2][n] + e4[r].w * we[3][n];
                wv[r] = f2b(fmaxf(v, 0.f));
            }
            *(u16x4*)&Ts[col * TSTR + row0] = wv;
        }
    }
    __syncthreads();

    // segmented column walk: thread t = column, runs of dstL
    if (t < 128) {
        int head = dstL[0], tail = dstL[127];
        bool headP = rowptr[head] < bRow;            // head segment starts before block
        bool tailP = rowptr[tail + 1] > bRow + 128;  // tail segment continues after block
        const unsigned short* tc = &Ts[t * TSTR];
        float a = 0.f;
        int node = head;
        for (int r = 0; r < 128; ++r) {
            int nr = dstL[r];
            if (nr != node) {
                if (node == head && headP) atomicAdd(&Agg[(long long)node * HD + t], a);
                else                       Agg[(long long)node * HD + t] = a;
                a = 0.f; node = nr;
            }
            a += b2f(tc[r]);
        }
        bool part = tailP || (node == head && headP);
        if (part) atomicAdd(&Agg[(long long)node * HD + t], a);
        else      Agg[(long long)node * HD + t] = a;
    }
}

// ---------------- node MFMA: row = [seg1 (D1 bf16) | seg2 (fp32)], stores bf16.
__global__ __launch_bounds__(256)
void mfma_node(const unsigned short* __restrict__ seg1, long long s1, int xoff, int D1,
               const float* __restrict__ seg2, long long s2,
               const unsigned short* __restrict__ WT, const float* __restrict__ bias,
               unsigned short* __restrict__ OutB, long long ostride, int ooff,
               int M, int K)
{
    __shared__ unsigned short As[4 * 128 * 8];
    __shared__ unsigned short Bs[4 * 128 * 8];

    const int t    = threadIdx.x;
    const int lane = t & 63;
    const int wid  = t >> 6;
    const int wm   = wid >> 1, wn = wid & 1;
    const int ln   = lane & 15, kb = lane >> 4;
    const int bRow = blockIdx.x * 128;

    const int srow = t >> 1, half = t & 1;
    int gr  = bRow + srow;
    int grc = gr < M ? gr : M - 1;
    const unsigned short* p1 = seg1 + (long long)grc * s1 + xoff;
    const float* p2 = seg2 + (long long)grc * s2;
    const unsigned short* pb = WT + (long long)srow * K;
    const int c0 = half * 2, c1 = half * 2 + 1;

    f32x4 acc[4][4];
    #pragma unroll
    for (int m = 0; m < 4; ++m)
        #pragma unroll
        for (int n = 0; n < 4; ++n) acc[m][n] = f32x4{0.f, 0.f, 0.f, 0.f};

    const int nkt = K >> 5;
    for (int kt = 0; kt < nkt; ++kt) {
        int k0 = (kt << 5) + half * 16;
        u16x8 a0, a1;
        if (k0 + 16 <= D1) {
            const u16x8* sp = (const u16x8*)(p1 + k0);
            a0 = sp[0]; a1 = sp[1];
        } else {
            const float* fp = p2 + (k0 - D1);
            #pragma unroll
            for (int j = 0; j < 8; ++j) { a0[j] = f2b(fp[j]); a1[j] = f2b(fp[8 + j]); }
        }
        *(u16x8*)&As[(c0 * 128 + srow) * 8] = a0;
        *(u16x8*)&As[(c1 * 128 + srow) * 8] = a1;
        const u16x8* bp = (const u16x8*)(pb + (kt << 5) + half * 16);
        u16x8 b0 = bp[0], b1 = bp[1];
        *(u16x8*)&Bs[(c0 * 128 + srow) * 8] = b0;
        *(u16x8*)&Bs[(c1 * 128 + srow) * 8] = b1;
        __syncthreads();

        s16x8 af[4], bfr[4];
        #pragma unroll
        for (int m = 0; m < 4; ++m)
            af[m] = *(const s16x8*)&As[(kb * 128 + wm * 64 + m * 16 + ln) * 8];
        #pragma unroll
        for (int n = 0; n < 4; ++n)
            bfr[n] = *(const s16x8*)&Bs[(kb * 128 + wn * 64 + n * 16 + ln) * 8];
        #pragma unroll
        for (int m = 0; m < 4; ++m)
            #pragma unroll
            for (int n = 0; n < 4; ++n)
                acc[m][n] = __builtin_amdgcn_mfma_f32_16x16x32_bf16(af[m], bfr[n], acc[m][n], 0, 0, 0);
        __syncthreads();
    }

    float bv[4];
    #pragma unroll
    for (int n = 0; n < 4; ++n) bv[n] = bias[wn * 64 + n * 16 + ln];

    #pragma unroll
    for (int m = 0; m < 4; ++m) {
        #pragma unroll
        for (int r = 0; r < 4; ++r) {
            int grow = bRow + wm * 64 + m * 16 + kb * 4 + r;
            if (grow < M) {
                unsigned short* op = OutB + (long long)grow * ostride + ooff;
                #pragma unroll
                for (int n = 0; n < 4; ++n)
                    op[wn * 64 + n * 16 + ln] = f2b(fmaxf(acc[m][n][r] + bv[n], 0.f));
            }
        }
    }
}

// ---------------- fp32 GEMM for layer 1 (small/odd K). Both segs bf16. Stores bf16.
__global__ __launch_bounds__(256, 4)
void gemm_layer(const unsigned short* __restrict__ base1, int s1, int D,
                const unsigned short* __restrict__ base2, int s2,
                const int* __restrict__ srcidx,
                const float* __restrict__ W, const float* __restrict__ bias,
                unsigned short* __restrict__ OutB, long long ostride, int ooff,
                int M, int Ktot)
{
    __shared__ float As[128][33];
    __shared__ float Bs[32 * 128];

    const int t  = threadIdx.x;
    const int tx = t & 15;
    const int ty = t >> 4;
    const int srow  = t >> 1;
    const int kbase = (t & 1) * 16;
    int gr  = blockIdx.x * 128 + srow;
    int grc = gr < M ? gr : M - 1;
    long long r1 = srcidx ? (long long)srcidx[grc] : (long long)grc;
    const unsigned short* p1 = base1 + r1 * s1;
    const unsigned short* p2 = base2 + (long long)grc * s2;

    float acc[8][8];
    #pragma unroll
    for (int i = 0; i < 8; ++i)
        #pragma unroll
        for (int u = 0; u < 8; ++u) acc[i][u] = 0.f;

    const int ntiles = (Ktot + 31) / 32;
    for (int kt = 0; kt < ntiles; ++kt) {
        #pragma unroll
        for (int i = 0; i < 16; ++i) {
            int gk = kt * 32 + kbase + i;
            float v = 0.f;
            if (gk < D) v = b2f(p1[gk]);
            else if (gk < Ktot) v = b2f(p2[gk - D]);
            As[srow][kbase + i] = v;
        }
        #pragma unroll
        for (int p = 0; p < 4; ++p) {
            int idx = (p * 256 + t) * 4;
            int kk  = idx >> 7;
            int nn  = idx & 127;
            int gk  = kt * 32 + kk;
            float4 v = {0.f, 0.f, 0.f, 0.f};
            if (gk < Ktot) v = *reinterpret_cast<const float4*>(W + (long long)gk * 128 + nn);
            *reinterpret_cast<float4*>(&Bs[kk * 128 + nn]) = v;
        }
        __syncthreads();
        #pragma unroll 8
        for (int kk = 0; kk < 32; ++kk) {
            float a[8], b[8];
            #pragma unroll
            for (int i = 0; i < 8; ++i) a[i] = As[ty * 8 + i][kk];
            #pragma unroll
            for (int u = 0; u < 8; ++u) b[u] = Bs[kk * 128 + tx + 16 * u];
            #pragma unroll
            for (int i = 0; i < 8; ++i)
                #pragma unroll
                for (int u = 0; u < 8; ++u)
                    acc[i][u] = fmaf(a[i], b[u], acc[i][u]);
        }
        __syncthreads();
    }

    float bv[8];
    #pragma unroll
    for (int u = 0; u < 8; ++u) bv[u] = bias[tx + 16 * u];

    #pragma unroll
    for (int i = 0; i < 8; ++i) {
        int orow = blockIdx.x * 128 + ty * 8 + i;
        if (orow < M) {
            unsigned short* op = OutB + (long long)orow * ostride + ooff;
            #pragma unroll
            for (int u = 0; u < 8; ++u)
                op[tx + 16 * u] = f2b(fmaxf(acc[i][u] + bv[u], 0.f));
        }
    }
}

// ---------------- last layer (Hout=8), sorted, no atomics
__global__ void edge_small_sorted(const unsigned short* __restrict__ x,
                                  const int* __restrict__ srcS, const float* __restrict__ eaS,
                                  const float* __restrict__ We, const float* __restrict__ be,
                                  unsigned short* __restrict__ msg8)
{
    __shared__ float sW[132 * 8];
    for (int idx = threadIdx.x; idx < 132 * 8; idx += 256) sW[idx] = We[idx];
    __syncthreads();
    int e = blockIdx.x * 256 + threadIdx.x;
    if (e >= NE) return;
    int src = srcS[e];
    float acc[8];
    #pragma unroll
    for (int j = 0; j < 8; ++j) acc[j] = be[j];
    const unsigned short* xr = x + (long long)src * HD;
    for (int k8 = 0; k8 < HD / 8; ++k8) {
        u16x8 v = *(const u16x8*)(xr + k8 * 8);
        #pragma unroll
        for (int c = 0; c < 8; ++c) {
            float f = b2f(v[c]);
            #pragma unroll
            for (int j = 0; j < 8; ++j)
                acc[j] = fmaf(f, sW[(k8 * 8 + c) * 8 + j], acc[j]);
        }
    }
    float4 e4 = *(const float4*)(eaS + (long long)e * 4);
    float ev[4] = {e4.x, e4.y, e4.z, e4.w};
    #pragma unroll
    for (int c = 0; c < 4; ++c)
        #pragma unroll
        for (int j = 0; j < 8; ++j)
            acc[j] = fmaf(ev[c], sW[(HD + c) * 8 + j], acc[j]);
    u16x8 o;
    #pragma unroll
    for (int j = 0; j < 8; ++j) o[j] = f2b(fmaxf(acc[j], 0.f));
    *(u16x8*)(msg8 + (long long)e * 8) = o;
}

__global__ void agg8_kernel(const unsigned short* __restrict__ msg8,
                            const int* __restrict__ rowptr, float* __restrict__ AggS)
{
    int t = threadIdx.x;
    int n = blockIdx.x * 32 + (t >> 3);
    int j = t & 7;
    if (n >= NN) return;
    int s = rowptr[n], e = rowptr[n + 1];
    float a = 0.f;
    for (int p = s; p < e; ++p) a += b2f(msg8[(long long)p * 8 + j]);
    AggS[(long long)n * 8 + j] = a;
}

__global__ void node_small(const unsigned short* __restrict__ x, const float* __restrict__ Agg,
                           const float* __restrict__ Wn, const float* __restrict__ bn,
                           float* __restrict__ out)
{
    __shared__ float sW[136 * 8];
    for (int idx = threadIdx.x; idx < 136 * 8; idx += 256) sW[idx] = Wn[idx];
    __syncthreads();
    int n = blockIdx.x * 256 + threadIdx.x;
    if (n >= NN) return;
    float acc[8];
    #pragma unroll
    for (int j = 0; j < 8; ++j) acc[j] = bn[j];
    const unsigned short* xr = x + (long long)n * HD;
    for (int k8 = 0; k8 < HD / 8; ++k8) {
        u16x8 v = *(const u16x8*)(xr + k8 * 8);
        #pragma unroll
        for (int c = 0; c < 8; ++c) {
            float f = b2f(v[c]);
            #pragma unroll
            for (int j = 0; j < 8; ++j)
                acc[j] = fmaf(f, sW[(k8 * 8 + c) * 8 + j], acc[j]);
        }
    }
    const float* ar = Agg + (long long)n * 8;
    #pragma unroll
    for (int c = 0; c < 8; ++c) {
        float v = ar[c];
        #pragma unroll
        for (int j = 0; j < 8; ++j)
            acc[j] = fmaf(v, sW[(HD + c) * 8 + j], acc[j]);
    }
    #pragma unroll
    for (int j = 0; j < 8; ++j)
        out[(long long)n * 8 + j] = fmaxf(acc[j], 0.f);
}

extern "C" void kernel_launch(void* const* d_in, const int* in_sizes, int n_in,
                              void* d_out, int out_size, void* d_ws, size_t ws_size,
                              hipStream_t stream) {
    const float* x    = (const float*)d_in[0];
    const int*   ei   = (const int*)d_in[1];
    const float* ea   = (const float*)d_in[2];
    const float* We1  = (const float*)d_in[3];
    const float* be1  = (const float*)d_in[4];
    const float* Wn1  = (const float*)d_in[5];
    const float* bn1  = (const float*)d_in[6];
    const float* WeM  = (const float*)d_in[7];
    const float* beM  = (const float*)d_in[8];
    const float* WnM  = (const float*)d_in[9];
    const float* bnM  = (const float*)d_in[10];
    const float* WeC  = (const float*)d_in[11];
    const float* beC  = (const float*)d_in[12];
    const float* WnC  = (const float*)d_in[13];
    const float* bnC  = (const float*)d_in[14];
    const float* WeL  = (const float*)d_in[15];
    const float* beL  = (const float*)d_in[16];
    const float* WnL  = (const float*)d_in[17];
    const float* bnL  = (const float*)d_in[18];

    char* w = (char*)d_ws;
    auto alloc = [&](size_t bytes) -> char* {
        char* p = w; w += (bytes + 255) & ~(size_t)255; return p;
    };
    int*            cnt    = (int*)           alloc((size_t)NN * 4);
    int*            cursor = (int*)           alloc((size_t)NN * 4);
    int*            rowptr = (int*)           alloc((size_t)(NN + 1) * 4);
    int*            srcS   = (int*)           alloc((size_t)NE * 4);
    int*            dstS   = (int*)           alloc((size_t)NE * 4);
    float*          eaS    = (float*)         alloc((size_t)NE * 4 * 4);
    unsigned short* eaSB   = (unsigned short*)alloc((size_t)NE * 4 * 2);
    unsigned short* msg    = (unsigned short*)alloc((size_t)NE * HD * 2);
    unsigned short* XB     = (unsigned short*)alloc((size_t)NN * 8 * 2);
    unsigned short* XS     = (unsigned short*)alloc((size_t)NN * 7 * HD * 2);
    unsigned short* HC     = (unsigned short*)alloc((size_t)NN * HD * 2);
    unsigned short* AggB   = (unsigned short*)alloc((size_t)NN * HD * 2);
    float*          AggF   = (float*)         alloc((size_t)NN * HD * 4);
    float*          AggS   = (float*)         alloc((size_t)NN * 8 * 4);
    unsigned short* msg8   = (unsigned short*)alloc((size_t)NE * 8 * 2);
    unsigned short* WTeM   = (unsigned short*)alloc((size_t)6 * HD * 128 * 2);
    unsigned short* WTeC   = (unsigned short*)alloc((size_t)HD * 896 * 2);
    unsigned short* WTnM   = (unsigned short*)alloc((size_t)6 * HD * 256 * 2);
    unsigned short* WTnC   = (unsigned short*)alloc((size_t)HD * 1024 * 2);
    float* out = (float*)d_out;

    // --- CSR build
    hipMemsetAsync(cnt, 0, (size_t)NN * 4, stream);
    hipMemsetAsync(cursor, 0, (size_t)NN * 4, stream);
    hist_kernel<<<(NE + 255) / 256, 256, 0, stream>>>(ei, cnt);
    scan_kernel<<<1, 256, 0, stream>>>(cnt, rowptr);
    scatter_kernel<<<(NE + 255) / 256, 256, 0, stream>>>(ei, ea, rowptr, cursor, srcS, dstS, eaS, eaSB);

    // --- weight conversions
    cvt_bf16<<<(NN * 8 + 255) / 256, 256, 0, stream>>>(x, XB, NN * 8);
    for (int i = 0; i < 6; ++i) {
        cvt_transpose<<<(128 * HD + 255) / 256, 256, 0, stream>>>(WeM + (size_t)i * 132 * HD, WTeM + (size_t)i * HD * 128, 128);
        cvt_transpose<<<(256 * HD + 255) / 256, 256, 0, stream>>>(WnM + (size_t)i * 256 * HD, WTnM + (size_t)i * HD * 256, 256);
    }
    cvt_transpose<<<(896 * HD + 255) / 256, 256, 0, stream>>>(WeC, WTeC, 896);
    cvt_transpose<<<(1024 * HD + 255) / 256, 256, 0, stream>>>(WnC, WTnC, 1024);

    const int egrid = NE / 128;            // 2500
    const int ngrid = (NN + 127) / 128;    // 157
    const int agrid = (NN + 15) / 16;      // 1250

    // --- layer 1 (fp32 path, K small/odd)
    gemm_layer<<<egrid, 256, 0, stream>>>(XB, 8, 8, eaSB, 4, srcS,
                                          We1, be1, msg, HD, 0, NE, 12);
    agg_kernel<<<agrid, 256, 0, stream>>>(msg, rowptr, AggB);
    gemm_layer<<<ngrid, 256, 0, stream>>>(XB, 8, 8, AggB, HD, nullptr,
                                          Wn1, bn1, XS, 7 * HD, 0, NN, 136);

    // layer-1 node output consumed as seg1; convert AggB path: node layer 2 uses
    // XS slice 0 (bf16) + AggF (fp32). For uniformity layer-2 onward uses AggF.

    // --- layers 2..7 (fused MFMA edge+agg, then node MFMA)
    for (int i = 0; i < 6; ++i) {
        hipMemsetAsync(AggF, 0, (size_t)NN * HD * 4, stream);
        mfma_edge_agg<<<egrid, 256, 0, stream>>>(XS, 7 * HD, i * HD, HD,
                                                 srcS, dstS, rowptr,
                                                 WTeM + (size_t)i * HD * 128, beM + i * HD,
                                                 WeM + (size_t)i * 132 * HD + (size_t)128 * HD, eaS,
                                                 AggF);
        mfma_node<<<ngrid, 256, 0, stream>>>(XS, 7 * HD, i * HD, HD,
                                             AggF, HD,
                                             WTnM + (size_t)i * HD * 256, bnM + i * HD,
                                             XS, 7 * HD, (i + 1) * HD, NN, 256);
    }

    // --- concat layer (K=896 / 1024)
    hipMemsetAsync(AggF, 0, (size_t)NN * HD * 4, stream);
    mfma_edge_agg<<<egrid, 256, 0, stream>>>(XS, 7 * HD, 0, 7 * HD,
                                             srcS, dstS, rowptr,
                                             WTeC, beC, WeC + (size_t)896 * HD, eaS,
                                             AggF);
    mfma_node<<<ngrid, 256, 0, stream>>>(XS, 7 * HD, 0, 7 * HD,
                                         AggF, HD,
                                         WTnC, bnC,
                                         HC, HD, 0, NN, 1024);

    // --- last layer (Hout=8), sorted + no atomics
    edge_small_sorted<<<NE / 256, 256, 0, stream>>>(HC, srcS, eaS, WeL, beL, msg8);
    agg8_kernel<<<(NN + 31) / 32, 256, 0, stream>>>(msg8, rowptr, AggS);
    node_small<<<(NN + 255) / 256, 256, 0, stream>>>(HC, AggS, WnL, bnL, out);
}

// Round 6
// 641.695 us; speedup vs baseline: 1.7396x; 1.7396x over previous
//
#include <hip/hip_runtime.h>

#define NN 20000
#define NE 320000
#define HD 128

typedef short     s16x8 __attribute__((ext_vector_type(8)));
typedef unsigned short u16x8 __attribute__((ext_vector_type(8)));
typedef float     f32x4 __attribute__((ext_vector_type(4)));

__device__ __forceinline__ float b2f(unsigned short u) {
    union { unsigned int i; float f; } c; c.i = ((unsigned int)u) << 16; return c.f;
}
__device__ __forceinline__ unsigned short f2b(float f) {
    union { float f; unsigned int i; } c; c.f = f;
    unsigned int x = c.i + 0x7FFFu + ((c.i >> 16) & 1u);
    return (unsigned short)(x >> 16);
}

// ---------------- CSR build (sort edges by dst) ----------------
__global__ void hist_kernel(const int* __restrict__ ei, int* __restrict__ cnt) {
    int e = blockIdx.x * 256 + threadIdx.x;
    if (e < NE) atomicAdd(&cnt[ei[NE + e]], 1);
}

__global__ void scan_kernel(const int* __restrict__ cnt, int* __restrict__ rowptr) {
    __shared__ int s[256];
    __shared__ int carry;
    int t = threadIdx.x;
    if (t == 0) carry = 0;
    __syncthreads();
    for (int base = 0; base < NN; base += 256) {
        int v = (base + t < NN) ? cnt[base + t] : 0;
        s[t] = v; __syncthreads();
        #pragma unroll
        for (int off = 1; off < 256; off <<= 1) {
            int add = (t >= off) ? s[t - off] : 0;
            __syncthreads();
            s[t] += add;
            __syncthreads();
        }
        int incl = s[t];
        if (base + t < NN) rowptr[base + t] = carry + incl - v;
        __syncthreads();
        if (t == 255) carry += incl;
        __syncthreads();
    }
    if (t == 0) rowptr[NN] = NE;
}

__global__ void scatter_kernel(const int* __restrict__ ei, const float* __restrict__ ea,
                               const int* __restrict__ rowptr, int* __restrict__ cursor,
                               int* __restrict__ srcS, float* __restrict__ eaS) {
    int e = blockIdx.x * 256 + threadIdx.x;
    if (e >= NE) return;
    int d = ei[NE + e];
    int pos = rowptr[d] + atomicAdd(&cursor[d], 1);
    srcS[pos] = ei[e];
    *(float4*)(eaS + (long long)pos * 4) = *(const float4*)(ea + (long long)e * 4);
}

// ---------------- weight transpose+convert: WT[l][n*K+k] = bf16(W[l][k*128+n])
__global__ void cvt_transpose_b(const float* __restrict__ W, unsigned short* __restrict__ WT,
                                int K, size_t Ws, size_t WTs) {
    const float* Wl = W + (size_t)blockIdx.y * Ws;
    unsigned short* WTl = WT + (size_t)blockIdx.y * WTs;
    int tid = blockIdx.x * 256 + threadIdx.x;
    if (tid >= K * HD) return;
    int n = tid & (HD - 1), k = tid >> 7;
    WTl[(size_t)n * K + k] = f2b(Wl[(size_t)k * HD + n]);
}

// ---------------- layer-1 projection: P1 = x @ We1[:8]  (no bias, no relu)
__global__ void proj8(const float* __restrict__ x, const float* __restrict__ W,
                      unsigned short* __restrict__ P) {
    int t = blockIdx.x * 256 + threadIdx.x;   // over NN*128
    int n = t >> 7, j = t & 127;
    const float* xr = x + (long long)n * 8;
    float a = 0.f;
    #pragma unroll
    for (int k = 0; k < 8; ++k) a = fmaf(xr[k], W[k * HD + j], a);
    P[t] = f2b(a);
}

// ---------------- fused edge pass: Agg[n] = sum_{e in n's edges} relu(P[src[e]] + ea[e]@Wea + bias)
__global__ __launch_bounds__(256)
void edge_agg(const unsigned short* __restrict__ P,     // [NN][128] bf16
              const int* __restrict__ srcS, const int* __restrict__ rowptr,
              const float* __restrict__ eaS,            // [NE][4] sorted
              const float* __restrict__ Wea,            // [4][128] fp32
              const float* __restrict__ bias,           // [128]
              float* __restrict__ AggF)                 // [NN][128] fp32
{
    int t  = threadIdx.x;
    int n  = blockIdx.x * 16 + (t >> 4);
    int cg = t & 15;
    float wea[4][8], bv[8];
    #pragma unroll
    for (int c = 0; c < 4; ++c)
        #pragma unroll
        for (int j = 0; j < 8; ++j) wea[c][j] = Wea[c * HD + cg * 8 + j];
    #pragma unroll
    for (int j = 0; j < 8; ++j) bv[j] = bias[cg * 8 + j];

    int s = rowptr[n], e = rowptr[n + 1];
    float acc[8];
    #pragma unroll
    for (int j = 0; j < 8; ++j) acc[j] = 0.f;
    for (int p = s; p < e; ++p) {
        int src = srcS[p];
        u16x8 pv = *(const u16x8*)(P + (long long)src * HD + cg * 8);
        float4 e4 = *(const float4*)(eaS + (long long)p * 4);
        #pragma unroll
        for (int j = 0; j < 8; ++j) {
            float m = b2f(pv[j]) + bv[j];
            m = fmaf(e4.x, wea[0][j], m);
            m = fmaf(e4.y, wea[1][j], m);
            m = fmaf(e4.z, wea[2][j], m);
            m = fmaf(e4.w, wea[3][j], m);
            acc[j] += fmaxf(m, 0.f);
        }
    }
    float4 o0 = {acc[0], acc[1], acc[2], acc[3]};
    float4 o1 = {acc[4], acc[5], acc[6], acc[7]};
    *(float4*)(AggF + (long long)n * HD + cg * 8)     = o0;
    *(float4*)(AggF + (long long)n * HD + cg * 8 + 4) = o1;
}

// ---------------- MFMA GEMM: Out = [relu](row @ W [+ bias]); row = [seg1 bf16 (D1) | seg2 fp32].
// ACT=true: +bias, relu. ACT=false: raw projection (bias unused). Output bf16.
template<bool ACT>
__global__ __launch_bounds__(256)
void mfma_node(const unsigned short* __restrict__ seg1, long long s1, int xoff, int D1,
               const float* __restrict__ seg2, long long s2,
               const unsigned short* __restrict__ WT, const float* __restrict__ bias,
               unsigned short* __restrict__ OutB, long long ostride, int ooff,
               int M, int K)
{
    __shared__ unsigned short As[4 * 128 * 8];
    __shared__ unsigned short Bs[4 * 128 * 8];

    const int t    = threadIdx.x;
    const int lane = t & 63;
    const int wid  = t >> 6;
    const int wm   = wid >> 1, wn = wid & 1;
    const int ln   = lane & 15, kb = lane >> 4;
    const int bRow = blockIdx.x * 128;

    const int srow = t >> 1, half = t & 1;
    int gr  = bRow + srow;
    int grc = gr < M ? gr : M - 1;
    const unsigned short* p1 = seg1 + (long long)grc * s1 + xoff;
    const float* p2 = seg2 + (long long)grc * s2;
    const unsigned short* pb = WT + (long long)srow * K;
    const int c0 = half * 2, c1 = half * 2 + 1;

    f32x4 acc[4][4];
    #pragma unroll
    for (int m = 0; m < 4; ++m)
        #pragma unroll
        for (int n = 0; n < 4; ++n) acc[m][n] = f32x4{0.f, 0.f, 0.f, 0.f};

    const int nkt = K >> 5;
    for (int kt = 0; kt < nkt; ++kt) {
        int k0 = (kt << 5) + half * 16;
        u16x8 a0, a1;
        if (k0 + 16 <= D1) {
            const u16x8* sp = (const u16x8*)(p1 + k0);
            a0 = sp[0]; a1 = sp[1];
        } else {
            const float* fp = p2 + (k0 - D1);
            #pragma unroll
            for (int j = 0; j < 8; ++j) { a0[j] = f2b(fp[j]); a1[j] = f2b(fp[8 + j]); }
        }
        *(u16x8*)&As[(c0 * 128 + srow) * 8] = a0;
        *(u16x8*)&As[(c1 * 128 + srow) * 8] = a1;
        const u16x8* bp = (const u16x8*)(pb + (kt << 5) + half * 16);
        u16x8 b0 = bp[0], b1 = bp[1];
        *(u16x8*)&Bs[(c0 * 128 + srow) * 8] = b0;
        *(u16x8*)&Bs[(c1 * 128 + srow) * 8] = b1;
        __syncthreads();

        s16x8 af[4], bfr[4];
        #pragma unroll
        for (int m = 0; m < 4; ++m)
            af[m] = *(const s16x8*)&As[(kb * 128 + wm * 64 + m * 16 + ln) * 8];
        #pragma unroll
        for (int n = 0; n < 4; ++n)
            bfr[n] = *(const s16x8*)&Bs[(kb * 128 + wn * 64 + n * 16 + ln) * 8];
        #pragma unroll
        for (int m = 0; m < 4; ++m)
            #pragma unroll
            for (int n = 0; n < 4; ++n)
                acc[m][n] = __builtin_amdgcn_mfma_f32_16x16x32_bf16(af[m], bfr[n], acc[m][n], 0, 0, 0);
        __syncthreads();
    }

    float bv[4];
    if (ACT) {
        #pragma unroll
        for (int n = 0; n < 4; ++n) bv[n] = bias[wn * 64 + n * 16 + ln];
    }

    #pragma unroll
    for (int m = 0; m < 4; ++m) {
        #pragma unroll
        for (int r = 0; r < 4; ++r) {
            int grow = bRow + wm * 64 + m * 16 + kb * 4 + r;
            if (grow < M) {
                unsigned short* op = OutB + (long long)grow * ostride + ooff;
                #pragma unroll
                for (int n = 0; n < 4; ++n) {
                    float v = acc[m][n][r];
                    if (ACT) v = fmaxf(v + bv[n], 0.f);
                    op[wn * 64 + n * 16 + ln] = f2b(v);
                }
            }
        }
    }
}

// ---------------- layer-1 node update (fp32 SIMD GEMM, K=136)
__global__ __launch_bounds__(256, 4)
void gemm_node1(const float* __restrict__ x,        // [NN][8]
                const float* __restrict__ Agg,      // [NN][128]
                const float* __restrict__ W,        // [136][128]
                const float* __restrict__ bias,
                unsigned short* __restrict__ OutB)  // XS, stride 7*HD
{
    __shared__ float As[128][33];
    __shared__ float Bs[32 * 128];

    const int t  = threadIdx.x;
    const int tx = t & 15;
    const int ty = t >> 4;
    const int srow  = t >> 1;
    const int kbase = (t & 1) * 16;
    int gr  = blockIdx.x * 128 + srow;
    int grc = gr < NN ? gr : NN - 1;
    const float* p1 = x + (long long)grc * 8;
    const float* p2 = Agg + (long long)grc * HD;

    float acc[8][8];
    #pragma unroll
    for (int i = 0; i < 8; ++i)
        #pragma unroll
        for (int u = 0; u < 8; ++u) acc[i][u] = 0.f;

    for (int kt = 0; kt < 5; ++kt) {
        #pragma unroll
        for (int i = 0; i < 16; ++i) {
            int gk = kt * 32 + kbase + i;
            float v = 0.f;
            if (gk < 8) v = p1[gk];
            else if (gk < 136) v = p2[gk - 8];
            As[srow][kbase + i] = v;
        }
        #pragma unroll
        for (int p = 0; p < 4; ++p) {
            int idx = (p * 256 + t) * 4;
            int kk  = idx >> 7;
            int nn  = idx & 127;
            int gk  = kt * 32 + kk;
            float4 v = {0.f, 0.f, 0.f, 0.f};
            if (gk < 136) v = *reinterpret_cast<const float4*>(W + (long long)gk * HD + nn);
            *reinterpret_cast<float4*>(&Bs[kk * 128 + nn]) = v;
        }
        __syncthreads();
        #pragma unroll 8
        for (int kk = 0; kk < 32; ++kk) {
            float a[8], b[8];
            #pragma unroll
            for (int i = 0; i < 8; ++i) a[i] = As[ty * 8 + i][kk];
            #pragma unroll
            for (int u = 0; u < 8; ++u) b[u] = Bs[kk * 128 + tx + 16 * u];
            #pragma unroll
            for (int i = 0; i < 8; ++i)
                #pragma unroll
                for (int u = 0; u < 8; ++u)
                    acc[i][u] = fmaf(a[i], b[u], acc[i][u]);
        }
        __syncthreads();
    }

    float bv[8];
    #pragma unroll
    for (int u = 0; u < 8; ++u) bv[u] = bias[tx + 16 * u];

    #pragma unroll
    for (int i = 0; i < 8; ++i) {
        int orow = blockIdx.x * 128 + ty * 8 + i;
        if (orow < NN) {
            unsigned short* op = OutB + (long long)orow * (7 * HD);
            #pragma unroll
            for (int u = 0; u < 8; ++u)
                op[tx + 16 * u] = f2b(fmaxf(acc[i][u] + bv[u], 0.f));
        }
    }
}

// ---------------- last layer: projection PL = HC @ WeL[:128]  (fp32, no bias)
__global__ void projL(const unsigned short* __restrict__ HC, const float* __restrict__ WeL,
                      float* __restrict__ PL) {
    __shared__ float sW[HD * 8];
    for (int i = threadIdx.x; i < HD * 8; i += 256) sW[i] = WeL[i];
    __syncthreads();
    int n = blockIdx.x * 256 + threadIdx.x;
    if (n >= NN) return;
    float a[8];
    #pragma unroll
    for (int j = 0; j < 8; ++j) a[j] = 0.f;
    const unsigned short* xr = HC + (long long)n * HD;
    for (int k8 = 0; k8 < HD / 8; ++k8) {
        u16x8 v = *(const u16x8*)(xr + k8 * 8);
        #pragma unroll
        for (int c = 0; c < 8; ++c) {
            float f = b2f(v[c]);
            #pragma unroll
            for (int j = 0; j < 8; ++j)
                a[j] = fmaf(f, sW[(k8 * 8 + c) * 8 + j], a[j]);
        }
    }
    float4 o0 = {a[0], a[1], a[2], a[3]};
    float4 o1 = {a[4], a[5], a[6], a[7]};
    *(float4*)(PL + (long long)n * 8)     = o0;
    *(float4*)(PL + (long long)n * 8 + 4) = o1;
}

// fused edge pass for Hout=8
__global__ void edge_agg8(const float* __restrict__ PL, const int* __restrict__ srcS,
                          const int* __restrict__ rowptr, const float* __restrict__ eaS,
                          const float* __restrict__ WeL, const float* __restrict__ beL,
                          float* __restrict__ AggS) {
    int t = threadIdx.x;
    int n = blockIdx.x * 32 + (t >> 3);
    int j = t & 7;
    float wea[4];
    #pragma unroll
    for (int c = 0; c < 4; ++c) wea[c] = WeL[(HD + c) * 8 + j];
    float bb = beL[j];
    int s = rowptr[n], e = rowptr[n + 1];
    float acc = 0.f;
    for (int p = s; p < e; ++p) {
        int src = srcS[p];
        float m = PL[(long long)src * 8 + j] + bb;
        float4 e4 = *(const float4*)(eaS + (long long)p * 4);
        m = fmaf(e4.x, wea[0], m);
        m = fmaf(e4.y, wea[1], m);
        m = fmaf(e4.z, wea[2], m);
        m = fmaf(e4.w, wea[3], m);
        acc += fmaxf(m, 0.f);
    }
    AggS[(long long)n * 8 + j] = acc;
}

__global__ void node_small(const unsigned short* __restrict__ x, const float* __restrict__ Agg,
                           const float* __restrict__ Wn, const float* __restrict__ bn,
                           float* __restrict__ out)
{
    __shared__ float sW[136 * 8];
    for (int idx = threadIdx.x; idx < 136 * 8; idx += 256) sW[idx] = Wn[idx];
    __syncthreads();
    int n = blockIdx.x * 256 + threadIdx.x;
    if (n >= NN) return;
    float acc[8];
    #pragma unroll
    for (int j = 0; j < 8; ++j) acc[j] = bn[j];
    const unsigned short* xr = x + (long long)n * HD;
    for (int k8 = 0; k8 < HD / 8; ++k8) {
        u16x8 v = *(const u16x8*)(xr + k8 * 8);
        #pragma unroll
        for (int c = 0; c < 8; ++c) {
            float f = b2f(v[c]);
            #pragma unroll
            for (int j = 0; j < 8; ++j)
                acc[j] = fmaf(f, sW[(k8 * 8 + c) * 8 + j], acc[j]);
        }
    }
    const float* ar = Agg + (long long)n * 8;
    #pragma unroll
    for (int c = 0; c < 8; ++c) {
        float v = ar[c];
        #pragma unroll
        for (int j = 0; j < 8; ++j)
            acc[j] = fmaf(v, sW[(HD + c) * 8 + j], acc[j]);
    }
    #pragma unroll
    for (int j = 0; j < 8; ++j)
        out[(long long)n * 8 + j] = fmaxf(acc[j], 0.f);
}

extern "C" void kernel_launch(void* const* d_in, const int* in_sizes, int n_in,
                              void* d_out, int out_size, void* d_ws, size_t ws_size,
                              hipStream_t stream) {
    const float* x    = (const float*)d_in[0];
    const int*   ei   = (const int*)d_in[1];
    const float* ea   = (const float*)d_in[2];
    const float* We1  = (const float*)d_in[3];
    const float* be1  = (const float*)d_in[4];
    const float* Wn1  = (const float*)d_in[5];
    const float* bn1  = (const float*)d_in[6];
    const float* WeM  = (const float*)d_in[7];
    const float* beM  = (const float*)d_in[8];
    const float* WnM  = (const float*)d_in[9];
    const float* bnM  = (const float*)d_in[10];
    const float* WeC  = (const float*)d_in[11];
    const float* beC  = (const float*)d_in[12];
    const float* WnC  = (const float*)d_in[13];
    const float* bnC  = (const float*)d_in[14];
    const float* WeL  = (const float*)d_in[15];
    const float* beL  = (const float*)d_in[16];
    const float* WnL  = (const float*)d_in[17];
    const float* bnL  = (const float*)d_in[18];

    char* w = (char*)d_ws;
    auto alloc = [&](size_t bytes) -> char* {
        char* p = w; w += (bytes + 255) & ~(size_t)255; return p;
    };
    int*            cnt    = (int*)           alloc((size_t)NN * 4);
    int*            cursor = (int*)           alloc((size_t)NN * 4);
    int*            rowptr = (int*)           alloc((size_t)(NN + 1) * 4);
    int*            srcS   = (int*)           alloc((size_t)NE * 4);
    float*          eaS    = (float*)         alloc((size_t)NE * 4 * 4);
    unsigned short* Pbuf   = (unsigned short*)alloc((size_t)NN * HD * 2);
    unsigned short* XS     = (unsigned short*)alloc((size_t)NN * 7 * HD * 2);
    unsigned short* HC     = (unsigned short*)alloc((size_t)NN * HD * 2);
    float*          AggF   = (float*)         alloc((size_t)NN * HD * 4);
    float*          AggS   = (float*)         alloc((size_t)NN * 8 * 4);
    float*          PL     = (float*)         alloc((size_t)NN * 8 * 4);
    unsigned short* WTeM   = (unsigned short*)alloc((size_t)6 * HD * 128 * 2);
    unsigned short* WTnM   = (unsigned short*)alloc((size_t)6 * HD * 256 * 2);
    unsigned short* WTeC   = (unsigned short*)alloc((size_t)HD * 896 * 2);
    unsigned short* WTnC   = (unsigned short*)alloc((size_t)HD * 1024 * 2);
    float* out = (float*)d_out;

    // --- CSR build
    hipMemsetAsync(cnt, 0, (size_t)NN * 4, stream);
    hipMemsetAsync(cursor, 0, (size_t)NN * 4, stream);
    hist_kernel<<<(NE + 255) / 256, 256, 0, stream>>>(ei, cnt);
    scan_kernel<<<1, 256, 0, stream>>>(cnt, rowptr);
    scatter_kernel<<<(NE + 255) / 256, 256, 0, stream>>>(ei, ea, rowptr, cursor, srcS, eaS);

    // --- weight transposes (bf16)
    cvt_transpose_b<<<dim3((128 * HD + 255) / 256, 6), 256, 0, stream>>>(
        WeM, WTeM, 128, (size_t)132 * HD, (size_t)HD * 128);
    cvt_transpose_b<<<dim3((256 * HD + 255) / 256, 6), 256, 0, stream>>>(
        WnM, WTnM, 256, (size_t)256 * HD, (size_t)HD * 256);
    cvt_transpose_b<<<dim3((896 * HD + 255) / 256, 1), 256, 0, stream>>>(
        WeC, WTeC, 896, 0, 0);
    cvt_transpose_b<<<dim3((1024 * HD + 255) / 256, 1), 256, 0, stream>>>(
        WnC, WTnC, 1024, 0, 0);

    const int ngrid = (NN + 127) / 128;    // 157
    const int agrid = NN / 16;             // 1250

    // --- layer 1
    proj8<<<NN * HD / 256, 256, 0, stream>>>(x, We1, Pbuf);
    edge_agg<<<agrid, 256, 0, stream>>>(Pbuf, srcS, rowptr, eaS, We1 + 8 * HD, be1, AggF);
    gemm_node1<<<ngrid, 256, 0, stream>>>(x, AggF, Wn1, bn1, XS);

    // --- layers 2..7
    for (int i = 0; i < 6; ++i) {
        mfma_node<false><<<ngrid, 256, 0, stream>>>(XS, 7 * HD, i * HD, HD,
                                                    nullptr, 0,
                                                    WTeM + (size_t)i * HD * 128, nullptr,
                                                    Pbuf, HD, 0, NN, 128);
        edge_agg<<<agrid, 256, 0, stream>>>(Pbuf, srcS, rowptr, eaS,
                                            WeM + (size_t)i * 132 * HD + (size_t)128 * HD,
                                            beM + i * HD, AggF);
        mfma_node<true><<<ngrid, 256, 0, stream>>>(XS, 7 * HD, i * HD, HD,
                                                   AggF, HD,
                                                   WTnM + (size_t)i * HD * 256, bnM + i * HD,
                                                   XS, 7 * HD, (i + 1) * HD, NN, 256);
    }

    // --- concat layer
    mfma_node<false><<<ngrid, 256, 0, stream>>>(XS, 7 * HD, 0, 7 * HD,
                                                nullptr, 0, WTeC, nullptr,
                                                Pbuf, HD, 0, NN, 896);
    edge_agg<<<agrid, 256, 0, stream>>>(Pbuf, srcS, rowptr, eaS,
                                        WeC + (size_t)896 * HD, beC, AggF);
    mfma_node<true><<<ngrid, 256, 0, stream>>>(XS, 7 * HD, 0, 7 * HD,
                                               AggF, HD, WTnC, bnC,
                                               HC, HD, 0, NN, 1024);

    // --- last layer (Hout=8)
    projL<<<(NN + 255) / 256, 256, 0, stream>>>(HC, WeL, PL);
    edge_agg8<<<NN / 32, 256, 0, stream>>>(PL, srcS, rowptr, eaS, WeL, beL, AggS);
    node_small<<<(NN + 255) / 256, 256, 0, stream>>>(HC, AggS, WnL, bnL, out);
}

// Round 7
// 556.293 us; speedup vs baseline: 2.0067x; 1.1535x over previous
//
#include <hip/hip_runtime.h>

#define NN 20000
#define NE 320000
#define HD 128
#define NBLK ((NN + 255) / 256)   // 79

typedef short     s16x8 __attribute__((ext_vector_type(8)));
typedef unsigned short u16x8 __attribute__((ext_vector_type(8)));
typedef float     f32x4 __attribute__((ext_vector_type(4)));

__device__ __forceinline__ float b2f(unsigned short u) {
    union { unsigned int i; float f; } c; c.i = ((unsigned int)u) << 16; return c.f;
}
__device__ __forceinline__ unsigned short f2b(float f) {
    union { float f; unsigned int i; } c; c.f = f;
    unsigned int x = c.i + 0x7FFFu + ((c.i >> 16) & 1u);
    return (unsigned short)(x >> 16);
}

// ---------------- CSR build (sort edges by dst) ----------------
__global__ void hist_kernel(const int* __restrict__ ei, int* __restrict__ cnt) {
    int e = blockIdx.x * 256 + threadIdx.x;
    if (e < NE) atomicAdd(&cnt[ei[NE + e]], 1);
}

// phase 1: block-local exclusive scan into rowptr, block sums into bsum
__global__ void scan1_kernel(const int* __restrict__ cnt, int* __restrict__ rowptr,
                             int* __restrict__ bsum) {
    __shared__ int s[256];
    int t = threadIdx.x;
    int i = blockIdx.x * 256 + t;
    int v = (i < NN) ? cnt[i] : 0;
    s[t] = v; __syncthreads();
    #pragma unroll
    for (int off = 1; off < 256; off <<= 1) {
        int add = (t >= off) ? s[t - off] : 0;
        __syncthreads();
        s[t] += add;
        __syncthreads();
    }
    if (i < NN) rowptr[i] = s[t] - v;
    if (t == 255) bsum[blockIdx.x] = s[t];
}

// phase 2: exclusive scan of NBLK block sums (single small block)
__global__ void scan2_kernel(int* __restrict__ bsum, int* __restrict__ boffs) {
    __shared__ int s[256];
    int t = threadIdx.x;
    int v = (t < NBLK) ? bsum[t] : 0;
    s[t] = v; __syncthreads();
    #pragma unroll
    for (int off = 1; off < 256; off <<= 1) {
        int add = (t >= off) ? s[t - off] : 0;
        __syncthreads();
        s[t] += add;
        __syncthreads();
    }
    if (t < NBLK) boffs[t] = s[t] - v;
}

// phase 3: add block offsets
__global__ void scan3_kernel(int* __restrict__ rowptr, const int* __restrict__ boffs) {
    int i = blockIdx.x * 256 + threadIdx.x;
    if (i < NN) rowptr[i] += boffs[blockIdx.x];
    if (i == 0) rowptr[NN] = NE;
}

__global__ void scatter_kernel(const int* __restrict__ ei, const float* __restrict__ ea,
                               const int* __restrict__ rowptr, int* __restrict__ cursor,
                               int* __restrict__ srcS, float* __restrict__ eaS) {
    int e = blockIdx.x * 256 + threadIdx.x;
    if (e >= NE) return;
    int d = ei[NE + e];
    int pos = rowptr[d] + atomicAdd(&cursor[d], 1);
    srcS[pos] = ei[e];
    *(float4*)(eaS + (long long)pos * 4) = *(const float4*)(ea + (long long)e * 4);
}

// ---------------- weight transpose+convert: WT[l][n*K+k] = bf16(W[l][k*128+n])
__global__ void cvt_transpose_b(const float* __restrict__ W, unsigned short* __restrict__ WT,
                                int K, size_t Ws, size_t WTs) {
    const float* Wl = W + (size_t)blockIdx.y * Ws;
    unsigned short* WTl = WT + (size_t)blockIdx.y * WTs;
    int tid = blockIdx.x * 256 + threadIdx.x;
    if (tid >= K * HD) return;
    int n = tid & (HD - 1), k = tid >> 7;
    WTl[(size_t)n * K + k] = f2b(Wl[(size_t)k * HD + n]);
}

// ---------------- layer-1 projection: P1 = x @ We1[:8]  (no bias, no relu)
__global__ void proj8(const float* __restrict__ x, const float* __restrict__ W,
                      unsigned short* __restrict__ P) {
    int t = blockIdx.x * 256 + threadIdx.x;   // over NN*128
    int n = t >> 7, j = t & 127;
    const float* xr = x + (long long)n * 8;
    float a = 0.f;
    #pragma unroll
    for (int k = 0; k < 8; ++k) a = fmaf(xr[k], W[k * HD + j], a);
    P[t] = f2b(a);
}

// ---------------- fused edge pass: AggB[n] = bf16( sum_e relu(P[src] + ea@Wea + bias) )
__global__ __launch_bounds__(256)
void edge_agg(const unsigned short* __restrict__ P,     // [NN][128] bf16
              const int* __restrict__ srcS, const int* __restrict__ rowptr,
              const float* __restrict__ eaS,            // [NE][4] sorted
              const float* __restrict__ Wea,            // [4][128] fp32
              const float* __restrict__ bias,           // [128]
              unsigned short* __restrict__ AggB)        // [NN][128] bf16
{
    int t  = threadIdx.x;
    int n  = blockIdx.x * 16 + (t >> 4);
    int cg = t & 15;
    float wea[4][8], bv[8];
    #pragma unroll
    for (int c = 0; c < 4; ++c)
        #pragma unroll
        for (int j = 0; j < 8; ++j) wea[c][j] = Wea[c * HD + cg * 8 + j];
    #pragma unroll
    for (int j = 0; j < 8; ++j) bv[j] = bias[cg * 8 + j];

    int s = rowptr[n], e = rowptr[n + 1];
    float acc[8];
    #pragma unroll
    for (int j = 0; j < 8; ++j) acc[j] = 0.f;
    for (int p = s; p < e; ++p) {
        int src = srcS[p];
        u16x8 pv = *(const u16x8*)(P + (long long)src * HD + cg * 8);
        float4 e4 = *(const float4*)(eaS + (long long)p * 4);
        #pragma unroll
        for (int j = 0; j < 8; ++j) {
            float m = b2f(pv[j]) + bv[j];
            m = fmaf(e4.x, wea[0][j], m);
            m = fmaf(e4.y, wea[1][j], m);
            m = fmaf(e4.z, wea[2][j], m);
            m = fmaf(e4.w, wea[3][j], m);
            acc[j] += fmaxf(m, 0.f);
        }
    }
    u16x8 o;
    #pragma unroll
    for (int j = 0; j < 8; ++j) o[j] = f2b(acc[j]);
    *(u16x8*)(AggB + (long long)n * HD + cg * 8) = o;
}

// ---------------- MFMA GEMM: Out = [relu](row @ W [+ bias]); row = [seg1 (D1) | seg2] both bf16.
template<bool ACT>
__global__ __launch_bounds__(256)
void mfma_node(const unsigned short* __restrict__ seg1, long long s1, int xoff, int D1,
               const unsigned short* __restrict__ seg2, long long s2,
               const unsigned short* __restrict__ WT, const float* __restrict__ bias,
               unsigned short* __restrict__ OutB, long long ostride, int ooff,
               int M, int K)
{
    __shared__ unsigned short As[4 * 128 * 8];
    __shared__ unsigned short Bs[4 * 128 * 8];

    const int t    = threadIdx.x;
    const int lane = t & 63;
    const int wid  = t >> 6;
    const int wm   = wid >> 1, wn = wid & 1;
    const int ln   = lane & 15, kb = lane >> 4;
    const int bRow = blockIdx.x * 128;

    const int srow = t >> 1, half = t & 1;
    int gr  = bRow + srow;
    int grc = gr < M ? gr : M - 1;
    const unsigned short* p1 = seg1 + (long long)grc * s1 + xoff;
    const unsigned short* p2 = seg2 ? seg2 + (long long)grc * s2 : nullptr;
    const unsigned short* pb = WT + (long long)srow * K;
    const int c0 = half * 2, c1 = half * 2 + 1;

    f32x4 acc[4][4];
    #pragma unroll
    for (int m = 0; m < 4; ++m)
        #pragma unroll
        for (int n = 0; n < 4; ++n) acc[m][n] = f32x4{0.f, 0.f, 0.f, 0.f};

    const int nkt = K >> 5;
    for (int kt = 0; kt < nkt; ++kt) {
        int k0 = (kt << 5) + half * 16;
        const u16x8* sp = (k0 + 16 <= D1) ? (const u16x8*)(p1 + k0)
                                          : (const u16x8*)(p2 + (k0 - D1));
        u16x8 a0 = sp[0], a1 = sp[1];
        *(u16x8*)&As[(c0 * 128 + srow) * 8] = a0;
        *(u16x8*)&As[(c1 * 128 + srow) * 8] = a1;
        const u16x8* bp = (const u16x8*)(pb + (kt << 5) + half * 16);
        u16x8 b0 = bp[0], b1 = bp[1];
        *(u16x8*)&Bs[(c0 * 128 + srow) * 8] = b0;
        *(u16x8*)&Bs[(c1 * 128 + srow) * 8] = b1;
        __syncthreads();

        s16x8 af[4], bfr[4];
        #pragma unroll
        for (int m = 0; m < 4; ++m)
            af[m] = *(const s16x8*)&As[(kb * 128 + wm * 64 + m * 16 + ln) * 8];
        #pragma unroll
        for (int n = 0; n < 4; ++n)
            bfr[n] = *(const s16x8*)&Bs[(kb * 128 + wn * 64 + n * 16 + ln) * 8];
        #pragma unroll
        for (int m = 0; m < 4; ++m)
            #pragma unroll
            for (int n = 0; n < 4; ++n)
                acc[m][n] = __builtin_amdgcn_mfma_f32_16x16x32_bf16(af[m], bfr[n], acc[m][n], 0, 0, 0);
        __syncthreads();
    }

    float bv[4];
    if (ACT) {
        #pragma unroll
        for (int n = 0; n < 4; ++n) bv[n] = bias[wn * 64 + n * 16 + ln];
    }

    #pragma unroll
    for (int m = 0; m < 4; ++m) {
        #pragma unroll
        for (int r = 0; r < 4; ++r) {
            int grow = bRow + wm * 64 + m * 16 + kb * 4 + r;
            if (grow < M) {
                unsigned short* op = OutB + (long long)grow * ostride + ooff;
                #pragma unroll
                for (int n = 0; n < 4; ++n) {
                    float v = acc[m][n][r];
                    if (ACT) v = fmaxf(v + bv[n], 0.f);
                    op[wn * 64 + n * 16 + ln] = f2b(v);
                }
            }
        }
    }
}

// ---------------- layer-1 node update (fp32 SIMD GEMM, K=136)
__global__ __launch_bounds__(256, 4)
void gemm_node1(const float* __restrict__ x,              // [NN][8]
                const unsigned short* __restrict__ Agg,   // [NN][128] bf16
                const float* __restrict__ W,              // [136][128]
                const float* __restrict__ bias,
                unsigned short* __restrict__ OutB)        // XS, stride 7*HD
{
    __shared__ float As[128][33];
    __shared__ float Bs[32 * 128];

    const int t  = threadIdx.x;
    const int tx = t & 15;
    const int ty = t >> 4;
    const int srow  = t >> 1;
    const int kbase = (t & 1) * 16;
    int gr  = blockIdx.x * 128 + srow;
    int grc = gr < NN ? gr : NN - 1;
    const float* p1 = x + (long long)grc * 8;
    const unsigned short* p2 = Agg + (long long)grc * HD;

    float acc[8][8];
    #pragma unroll
    for (int i = 0; i < 8; ++i)
        #pragma unroll
        for (int u = 0; u < 8; ++u) acc[i][u] = 0.f;

    for (int kt = 0; kt < 5; ++kt) {
        #pragma unroll
        for (int i = 0; i < 16; ++i) {
            int gk = kt * 32 + kbase + i;
            float v = 0.f;
            if (gk < 8) v = p1[gk];
            else if (gk < 136) v = b2f(p2[gk - 8]);
            As[srow][kbase + i] = v;
        }
        #pragma unroll
        for (int p = 0; p < 4; ++p) {
            int idx = (p * 256 + t) * 4;
            int kk  = idx >> 7;
            int nn  = idx & 127;
            int gk  = kt * 32 + kk;
            float4 v = {0.f, 0.f, 0.f, 0.f};
            if (gk < 136) v = *reinterpret_cast<const float4*>(W + (long long)gk * HD + nn);
            *reinterpret_cast<float4*>(&Bs[kk * 128 + nn]) = v;
        }
        __syncthreads();
        #pragma unroll 8
        for (int kk = 0; kk < 32; ++kk) {
            float a[8], b[8];
            #pragma unroll
            for (int i = 0; i < 8; ++i) a[i] = As[ty * 8 + i][kk];
            #pragma unroll
            for (int u = 0; u < 8; ++u) b[u] = Bs[kk * 128 + tx + 16 * u];
            #pragma unroll
            for (int i = 0; i < 8; ++i)
                #pragma unroll
                for (int u = 0; u < 8; ++u)
                    acc[i][u] = fmaf(a[i], b[u], acc[i][u]);
        }
        __syncthreads();
    }

    float bv[8];
    #pragma unroll
    for (int u = 0; u < 8; ++u) bv[u] = bias[tx + 16 * u];

    #pragma unroll
    for (int i = 0; i < 8; ++i) {
        int orow = blockIdx.x * 128 + ty * 8 + i;
        if (orow < NN) {
            unsigned short* op = OutB + (long long)orow * (7 * HD);
            #pragma unroll
            for (int u = 0; u < 8; ++u)
                op[tx + 16 * u] = f2b(fmaxf(acc[i][u] + bv[u], 0.f));
        }
    }
}

// ---------------- last layer: projection PL = HC @ WeL[:128]  (fp32, no bias)
__global__ void projL(const unsigned short* __restrict__ HC, const float* __restrict__ WeL,
                      float* __restrict__ PL) {
    __shared__ float sW[HD * 8];
    for (int i = threadIdx.x; i < HD * 8; i += 256) sW[i] = WeL[i];
    __syncthreads();
    int n = blockIdx.x * 256 + threadIdx.x;
    if (n >= NN) return;
    float a[8];
    #pragma unroll
    for (int j = 0; j < 8; ++j) a[j] = 0.f;
    const unsigned short* xr = HC + (long long)n * HD;
    for (int k8 = 0; k8 < HD / 8; ++k8) {
        u16x8 v = *(const u16x8*)(xr + k8 * 8);
        #pragma unroll
        for (int c = 0; c < 8; ++c) {
            float f = b2f(v[c]);
            #pragma unroll
            for (int j = 0; j < 8; ++j)
                a[j] = fmaf(f, sW[(k8 * 8 + c) * 8 + j], a[j]);
        }
    }
    float4 o0 = {a[0], a[1], a[2], a[3]};
    float4 o1 = {a[4], a[5], a[6], a[7]};
    *(float4*)(PL + (long long)n * 8)     = o0;
    *(float4*)(PL + (long long)n * 8 + 4) = o1;
}

// fused edge pass for Hout=8
__global__ void edge_agg8(const float* __restrict__ PL, const int* __restrict__ srcS,
                          const int* __restrict__ rowptr, const float* __restrict__ eaS,
                          const float* __restrict__ WeL, const float* __restrict__ beL,
                          float* __restrict__ AggS) {
    int t = threadIdx.x;
    int n = blockIdx.x * 32 + (t >> 3);
    int j = t & 7;
    float wea[4];
    #pragma unroll
    for (int c = 0; c < 4; ++c) wea[c] = WeL[(HD + c) * 8 + j];
    float bb = beL[j];
    int s = rowptr[n], e = rowptr[n + 1];
    float acc = 0.f;
    for (int p = s; p < e; ++p) {
        int src = srcS[p];
        float m = PL[(long long)src * 8 + j] + bb;
        float4 e4 = *(const float4*)(eaS + (long long)p * 4);
        m = fmaf(e4.x, wea[0], m);
        m = fmaf(e4.y, wea[1], m);
        m = fmaf(e4.z, wea[2], m);
        m = fmaf(e4.w, wea[3], m);
        acc += fmaxf(m, 0.f);
    }
    AggS[(long long)n * 8 + j] = acc;
}

__global__ void node_small(const unsigned short* __restrict__ x, const float* __restrict__ Agg,
                           const float* __restrict__ Wn, const float* __restrict__ bn,
                           float* __restrict__ out)
{
    __shared__ float sW[136 * 8];
    for (int idx = threadIdx.x; idx < 136 * 8; idx += 256) sW[idx] = Wn[idx];
    __syncthreads();
    int n = blockIdx.x * 256 + threadIdx.x;
    if (n >= NN) return;
    float acc[8];
    #pragma unroll
    for (int j = 0; j < 8; ++j) acc[j] = bn[j];
    const unsigned short* xr = x + (long long)n * HD;
    for (int k8 = 0; k8 < HD / 8; ++k8) {
        u16x8 v = *(const u16x8*)(xr + k8 * 8);
        #pragma unroll
        for (int c = 0; c < 8; ++c) {
            float f = b2f(v[c]);
            #pragma unroll
            for (int j = 0; j < 8; ++j)
                acc[j] = fmaf(f, sW[(k8 * 8 + c) * 8 + j], acc[j]);
        }
    }
    const float* ar = Agg + (long long)n * 8;
    #pragma unroll
    for (int c = 0; c < 8; ++c) {
        float v = ar[c];
        #pragma unroll
        for (int j = 0; j < 8; ++j)
            acc[j] = fmaf(v, sW[(HD + c) * 8 + j], acc[j]);
    }
    #pragma unroll
    for (int j = 0; j < 8; ++j)
        out[(long long)n * 8 + j] = fmaxf(acc[j], 0.f);
}

extern "C" void kernel_launch(void* const* d_in, const int* in_sizes, int n_in,
                              void* d_out, int out_size, void* d_ws, size_t ws_size,
                              hipStream_t stream) {
    const float* x    = (const float*)d_in[0];
    const int*   ei   = (const int*)d_in[1];
    const float* ea   = (const float*)d_in[2];
    const float* We1  = (const float*)d_in[3];
    const float* be1  = (const float*)d_in[4];
    const float* Wn1  = (const float*)d_in[5];
    const float* bn1  = (const float*)d_in[6];
    const float* WeM  = (const float*)d_in[7];
    const float* beM  = (const float*)d_in[8];
    const float* WnM  = (const float*)d_in[9];
    const float* bnM  = (const float*)d_in[10];
    const float* WeC  = (const float*)d_in[11];
    const float* beC  = (const float*)d_in[12];
    const float* WnC  = (const float*)d_in[13];
    const float* bnC  = (const float*)d_in[14];
    const float* WeL  = (const float*)d_in[15];
    const float* beL  = (const float*)d_in[16];
    const float* WnL  = (const float*)d_in[17];
    const float* bnL  = (const float*)d_in[18];

    char* w = (char*)d_ws;
    auto alloc = [&](size_t bytes) -> char* {
        char* p = w; w += (bytes + 255) & ~(size_t)255; return p;
    };
    int*            cnt    = (int*)           alloc((size_t)NN * 4);
    int*            cursor = (int*)           alloc((size_t)NN * 4);
    int*            rowptr = (int*)           alloc((size_t)(NN + 1) * 4);
    int*            bsum   = (int*)           alloc((size_t)256 * 4);
    int*            boffs  = (int*)           alloc((size_t)256 * 4);
    int*            srcS   = (int*)           alloc((size_t)NE * 4);
    float*          eaS    = (float*)         alloc((size_t)NE * 4 * 4);
    unsigned short* Pbuf   = (unsigned short*)alloc((size_t)NN * HD * 2);
    unsigned short* XS     = (unsigned short*)alloc((size_t)NN * 7 * HD * 2);
    unsigned short* HC     = (unsigned short*)alloc((size_t)NN * HD * 2);
    unsigned short* AggB   = (unsigned short*)alloc((size_t)NN * HD * 2);
    float*          AggS   = (float*)         alloc((size_t)NN * 8 * 4);
    float*          PL     = (float*)         alloc((size_t)NN * 8 * 4);
    unsigned short* WTeM   = (unsigned short*)alloc((size_t)6 * HD * 128 * 2);
    unsigned short* WTnM   = (unsigned short*)alloc((size_t)6 * HD * 256 * 2);
    unsigned short* WTeC   = (unsigned short*)alloc((size_t)HD * 896 * 2);
    unsigned short* WTnC   = (unsigned short*)alloc((size_t)HD * 1024 * 2);
    float* out = (float*)d_out;

    // --- CSR build (parallel scan)
    hipMemsetAsync(cnt, 0, (size_t)NN * 4, stream);
    hipMemsetAsync(cursor, 0, (size_t)NN * 4, stream);
    hist_kernel<<<(NE + 255) / 256, 256, 0, stream>>>(ei, cnt);
    scan1_kernel<<<NBLK, 256, 0, stream>>>(cnt, rowptr, bsum);
    scan2_kernel<<<1, 256, 0, stream>>>(bsum, boffs);
    scan3_kernel<<<NBLK, 256, 0, stream>>>(rowptr, boffs);
    scatter_kernel<<<(NE + 255) / 256, 256, 0, stream>>>(ei, ea, rowptr, cursor, srcS, eaS);

    // --- weight transposes (bf16)
    cvt_transpose_b<<<dim3((128 * HD + 255) / 256, 6), 256, 0, stream>>>(
        WeM, WTeM, 128, (size_t)132 * HD, (size_t)HD * 128);
    cvt_transpose_b<<<dim3((256 * HD + 255) / 256, 6), 256, 0, stream>>>(
        WnM, WTnM, 256, (size_t)256 * HD, (size_t)HD * 256);
    cvt_transpose_b<<<dim3((896 * HD + 255) / 256, 1), 256, 0, stream>>>(
        WeC, WTeC, 896, 0, 0);
    cvt_transpose_b<<<dim3((1024 * HD + 255) / 256, 1), 256, 0, stream>>>(
        WnC, WTnC, 1024, 0, 0);

    const int ngrid = (NN + 127) / 128;    // 157
    const int agrid = NN / 16;             // 1250

    // --- layer 1
    proj8<<<NN * HD / 256, 256, 0, stream>>>(x, We1, Pbuf);
    edge_agg<<<agrid, 256, 0, stream>>>(Pbuf, srcS, rowptr, eaS, We1 + 8 * HD, be1, AggB);
    gemm_node1<<<ngrid, 256, 0, stream>>>(x, AggB, Wn1, bn1, XS);

    // --- layers 2..7
    for (int i = 0; i < 6; ++i) {
        mfma_node<false><<<ngrid, 256, 0, stream>>>(XS, 7 * HD, i * HD, HD,
                                                    nullptr, 0,
                                                    WTeM + (size_t)i * HD * 128, nullptr,
                                                    Pbuf, HD, 0, NN, 128);
        edge_agg<<<agrid, 256, 0, stream>>>(Pbuf, srcS, rowptr, eaS,
                                            WeM + (size_t)i * 132 * HD + (size_t)128 * HD,
                                            beM + i * HD, AggB);
        mfma_node<true><<<ngrid, 256, 0, stream>>>(XS, 7 * HD, i * HD, HD,
                                                   AggB, HD,
                                                   WTnM + (size_t)i * HD * 256, bnM + i * HD,
                                                   XS, 7 * HD, (i + 1) * HD, NN, 256);
    }

    // --- concat layer
    mfma_node<false><<<ngrid, 256, 0, stream>>>(XS, 7 * HD, 0, 7 * HD,
                                                nullptr, 0, WTeC, nullptr,
                                                Pbuf, HD, 0, NN, 896);
    edge_agg<<<agrid, 256, 0, stream>>>(Pbuf, srcS, rowptr, eaS,
                                        WeC + (size_t)896 * HD, beC, AggB);
    mfma_node<true><<<ngrid, 256, 0, stream>>>(XS, 7 * HD, 0, 7 * HD,
                                               AggB, HD, WTnC, bnC,
                                               HC, HD, 0, NN, 1024);

    // --- last layer (Hout=8)
    projL<<<(NN + 255) / 256, 256, 0, stream>>>(HC, WeL, PL);
    edge_agg8<<<NN / 32, 256, 0, stream>>>(PL, srcS, rowptr, eaS, WeL, beL, AggS);
    node_small<<<(NN + 255) / 256, 256, 0, stream>>>(HC, AggS, WnL, bnL, out);
}